// Round 14
// baseline (377.585 us; speedup 1.0000x reference)
//
#include <hip/hip_runtime.h>

#define HC 128      // hidden / latent channels
#define FIN 64
#define DHID 1024
#define ZK 134      // LAT + 6
#define ZKP 160     // ZK padded to multiple of 32 for MFMA head

typedef __attribute__((ext_vector_type(8))) short short8;
typedef __attribute__((ext_vector_type(8))) __bf16 bf16x8;
typedef __attribute__((ext_vector_type(4))) float f32x4;
typedef __attribute__((ext_vector_type(8))) unsigned short u16x8;
typedef __attribute__((ext_vector_type(4))) unsigned short u16x4;

union FragU { short8 s; bf16x8 b; u16x8 u; };

__device__ inline unsigned short rne_bf16(float x) {
    union { float f; unsigned u; } v; v.f = x;
    unsigned u = v.u;
    unsigned r = (u + 0x7fffu + ((u >> 16) & 1u)) >> 16;
    return (unsigned short)r;
}
__device__ inline float bf16_to_f(unsigned short h) {
    union { unsigned u; float f; } v; v.u = ((unsigned)h) << 16;
    return v.f;
}

// ---------------------------------------------------------------- degree + per-edge rank
__global__ void k_deg_rank(const int* __restrict__ dst, int* __restrict__ cnt,
                           int* __restrict__ rank, int E) {
    int i = blockIdx.x * blockDim.x + threadIdx.x;
    if (i < E) rank[i] = atomicAdd(&cnt[dst[i]], 1);
}

// x fp32 -> bf16 table, pre-scaled by dinv[row]
__global__ void k_xtobf(const float* __restrict__ x, const float* __restrict__ dinv,
                        unsigned short* __restrict__ xb, int n4) {
    int i = blockIdx.x * blockDim.x + threadIdx.x;
    if (i >= n4) return;
    float d = dinv[i / (FIN / 4)];
    float4 v = ((const float4*)x)[i];
    u16x4 o;
    o[0] = rne_bf16(v.x * d); o[1] = rne_bf16(v.y * d);
    o[2] = rne_bf16(v.z * d); o[3] = rne_bf16(v.w * d);
    ((u16x4*)xb)[i] = o;
}

// ---------------------------------------------------------------- scan (CSR row offsets) + dinv
__global__ void k_scan1(const int* __restrict__ cnt, int* __restrict__ part,
                        int* __restrict__ bsum, float* __restrict__ dinv, int N) {
    __shared__ int sh[256];
    int t = threadIdx.x, i = blockIdx.x * 256 + t;
    int v = (i < N) ? cnt[i] : 0;
    if (i < N) dinv[i] = rsqrtf((float)v + 1.0f);
    sh[t] = v; __syncthreads();
    #pragma unroll
    for (int off = 1; off < 256; off <<= 1) {
        int tv = (t >= off) ? sh[t - off] : 0;
        __syncthreads();
        sh[t] += tv;
        __syncthreads();
    }
    if (i < N) part[i] = sh[t] - v;
    if (t == 255) bsum[blockIdx.x] = sh[255];
}

// merged scan2+scan3: each block computes its bsum prefix itself (nb <= 256)
__global__ void k_scan23(const int* __restrict__ part, const int* __restrict__ bsum,
                         int* __restrict__ row_start, int nb, int N) {
    __shared__ int sh[256];
    int t = threadIdx.x, b = blockIdx.x;
    sh[t] = (t < b && t < nb) ? bsum[t] : 0;
    __syncthreads();
    #pragma unroll
    for (int off = 128; off > 0; off >>= 1) {
        if (t < off) sh[t] += sh[t + off];
        __syncthreads();
    }
    int prefix = sh[0];
    int i = b * 256 + t;
    if (i < N) row_start[i] = part[i] + prefix;
}

// atomic-free scatter: pos = row_start[d] + rank[e]
__global__ void k_scatter3(const int* __restrict__ src, const int* __restrict__ dst,
                           const int* __restrict__ rank, const int* __restrict__ row_start,
                           int* __restrict__ csr, int E) {
    int e = blockIdx.x * blockDim.x + threadIdx.x;
    if (e >= E) return;
    int d = dst[e];
    csr[row_start[d] + rank[e]] = src[e];
}

// ---------------------------------------------------------------- gather (pre-scaled bf16 table)
// agg[d] = dinv[d]*(T'[d] + sum T'[src]).  Lanes per node L = RF/8 (16B u16x8 loads).
// STATS (RF=128 only): grid-strided, named-register partials -> LDS grid -> one global
// atomic phase per block (block count kept ~1024: round-12 lesson, ~17ns/serialized atomic).
template <int RF, bool STATS>
__global__ __launch_bounds__(256) void k_gather4(const unsigned short* __restrict__ T,
                                                 const int* __restrict__ csr,
                                                 const int* __restrict__ row_start,
                                                 const int* __restrict__ cnt,
                                                 const float* __restrict__ dinv,
                                                 unsigned short* __restrict__ agg,
                                                 float* __restrict__ stat, int N) {
    constexpr int L = RF / 8;          // lanes per node
    constexpr int NPB = 256 / L;       // nodes per block-iteration
    int tid = threadIdx.x;
    int slot = tid / L, q = tid % L;
    int numGrp = (N + NPB - 1) / NPB;
    float s0=0.f,s1=0.f,s2=0.f,s3=0.f,s4=0.f,s5=0.f,s6=0.f,s7=0.f;
    float p0=0.f,p1=0.f,p2=0.f,p3=0.f,p4=0.f,p5=0.f,p6=0.f,p7=0.f;

    for (int grp = blockIdx.x; grp < numGrp; grp += gridDim.x) {
        int node = grp * NPB + slot;
        if (node >= N) continue;
        int beg = row_start[node];
        int end = beg + cnt[node];
        float d = dinv[node];
        u16x8 sv = ((const u16x8*)(T + (size_t)node * RF))[q];
        float acc[8];
        #pragma unroll
        for (int i = 0; i < 8; ++i) acc[i] = bf16_to_f(sv[i]);
        int j = beg;
        for (; j + 8 <= end; j += 8) {
            int e0 = csr[j], e1 = csr[j+1], e2 = csr[j+2], e3 = csr[j+3];
            int e4 = csr[j+4], e5 = csr[j+5], e6 = csr[j+6], e7 = csr[j+7];
            u16x8 v0 = ((const u16x8*)(T + (size_t)e0 * RF))[q];
            u16x8 v1 = ((const u16x8*)(T + (size_t)e1 * RF))[q];
            u16x8 v2 = ((const u16x8*)(T + (size_t)e2 * RF))[q];
            u16x8 v3 = ((const u16x8*)(T + (size_t)e3 * RF))[q];
            u16x8 v4 = ((const u16x8*)(T + (size_t)e4 * RF))[q];
            u16x8 v5 = ((const u16x8*)(T + (size_t)e5 * RF))[q];
            u16x8 v6 = ((const u16x8*)(T + (size_t)e6 * RF))[q];
            u16x8 v7 = ((const u16x8*)(T + (size_t)e7 * RF))[q];
            #pragma unroll
            for (int i = 0; i < 8; ++i) {
                acc[i] += (bf16_to_f(v0[i]) + bf16_to_f(v1[i]))
                        + (bf16_to_f(v2[i]) + bf16_to_f(v3[i]))
                        + (bf16_to_f(v4[i]) + bf16_to_f(v5[i]))
                        + (bf16_to_f(v6[i]) + bf16_to_f(v7[i]));
            }
        }
        for (; j + 2 <= end; j += 2) {
            int e0 = csr[j], e1 = csr[j + 1];
            u16x8 v0 = ((const u16x8*)(T + (size_t)e0 * RF))[q];
            u16x8 v1 = ((const u16x8*)(T + (size_t)e1 * RF))[q];
            #pragma unroll
            for (int i = 0; i < 8; ++i)
                acc[i] += bf16_to_f(v0[i]) + bf16_to_f(v1[i]);
        }
        if (j < end) {
            int e0 = csr[j];
            u16x8 v0 = ((const u16x8*)(T + (size_t)e0 * RF))[q];
            #pragma unroll
            for (int i = 0; i < 8; ++i) acc[i] += bf16_to_f(v0[i]);
        }
        u16x8 o;
        #pragma unroll
        for (int i = 0; i < 8; ++i) o[i] = rne_bf16(acc[i] * d);
        ((u16x8*)(agg + (size_t)node * RF))[q] = o;
        if (STATS) {
            float f;
            f = bf16_to_f(o[0]); s0 += f; p0 += f * f;
            f = bf16_to_f(o[1]); s1 += f; p1 += f * f;
            f = bf16_to_f(o[2]); s2 += f; p2 += f * f;
            f = bf16_to_f(o[3]); s3 += f; p3 += f * f;
            f = bf16_to_f(o[4]); s4 += f; p4 += f * f;
            f = bf16_to_f(o[5]); s5 += f; p5 += f * f;
            f = bf16_to_f(o[6]); s6 += f; p6 += f * f;
            f = bf16_to_f(o[7]); s7 += f; p7 += f * f;
        }
    }

    if (STATS) {   // RF == 128 path only (slot in 0..15)
        __shared__ float sh[16][136];
        int c0 = q * 8;
        sh[slot][c0+0]=s0; sh[slot][c0+1]=s1; sh[slot][c0+2]=s2; sh[slot][c0+3]=s3;
        sh[slot][c0+4]=s4; sh[slot][c0+5]=s5; sh[slot][c0+6]=s6; sh[slot][c0+7]=s7;
        __syncthreads();
        if (tid < HC) {
            float tot = 0.f;
            #pragma unroll
            for (int r = 0; r < 16; ++r) tot += sh[r][tid];
            atomicAdd(&stat[tid], tot);
        }
        __syncthreads();
        sh[slot][c0+0]=p0; sh[slot][c0+1]=p1; sh[slot][c0+2]=p2; sh[slot][c0+3]=p3;
        sh[slot][c0+4]=p4; sh[slot][c0+5]=p5; sh[slot][c0+6]=p6; sh[slot][c0+7]=p7;
        __syncthreads();
        if (tid < HC) {
            float tot = 0.f;
            #pragma unroll
            for (int r = 0; r < 16; ++r) tot += sh[r][tid];
            atomicAdd(&stat[HC + tid], tot);
        }
    }
}

// ---------------------------------------------------------------- batchnorm stats (layer 1: on gemm output)
__global__ __launch_bounds__(256) void k_bn_reduce3(const unsigned short* __restrict__ x,
                                                    float* __restrict__ stat, int N) {
    int cg = threadIdx.x & 15;
    int rr = threadIdx.x >> 4;
    int rpb = (N + gridDim.x - 1) / gridDim.x;
    int r0 = blockIdx.x * rpb;
    int r1 = min(N, r0 + rpb);
    float s0=0.f,s1=0.f,s2=0.f,s3=0.f,s4=0.f,s5=0.f,s6=0.f,s7=0.f;
    float q0=0.f,q1=0.f,q2=0.f,q3=0.f,q4=0.f,q5=0.f,q6=0.f,q7=0.f;
    for (int r = r0 + rr; r < r1; r += 16) {
        u16x8 v = *(const u16x8*)(x + (size_t)r * HC + cg * 8);
        float f;
        f = bf16_to_f(v[0]); s0 += f; q0 += f * f;
        f = bf16_to_f(v[1]); s1 += f; q1 += f * f;
        f = bf16_to_f(v[2]); s2 += f; q2 += f * f;
        f = bf16_to_f(v[3]); s3 += f; q3 += f * f;
        f = bf16_to_f(v[4]); s4 += f; q4 += f * f;
        f = bf16_to_f(v[5]); s5 += f; q5 += f * f;
        f = bf16_to_f(v[6]); s6 += f; q6 += f * f;
        f = bf16_to_f(v[7]); s7 += f; q7 += f * f;
    }
    __shared__ float sh[16][136];
    int c0 = cg * 8;
    int tid = threadIdx.x;
    sh[rr][c0+0]=s0; sh[rr][c0+1]=s1; sh[rr][c0+2]=s2; sh[rr][c0+3]=s3;
    sh[rr][c0+4]=s4; sh[rr][c0+5]=s5; sh[rr][c0+6]=s6; sh[rr][c0+7]=s7;
    __syncthreads();
    if (tid < HC) {
        float tot = 0.f;
        #pragma unroll
        for (int r2 = 0; r2 < 16; ++r2) tot += sh[r2][tid];
        atomicAdd(&stat[tid], tot);
    }
    __syncthreads();
    sh[rr][c0+0]=q0; sh[rr][c0+1]=q1; sh[rr][c0+2]=q2; sh[rr][c0+3]=q3;
    sh[rr][c0+4]=q4; sh[rr][c0+5]=q5; sh[rr][c0+6]=q6; sh[rr][c0+7]=q7;
    __syncthreads();
    if (tid < HC) {
        float tot = 0.f;
        #pragma unroll
        for (int r2 = 0; r2 < 16; ++r2) tot += sh[r2][tid];
        atomicAdd(&stat[HC + tid], tot);
    }
}

// in-place BN+ReLU on bf16 table; scale/shift recomputed inline from stats
__global__ void k_bn_apply3(unsigned short* __restrict__ t, const float* __restrict__ stat,
                            const float* __restrict__ gam, const float* __restrict__ bet,
                            float invN, int total8) {
    int i = blockIdx.x * blockDim.x + threadIdx.x;
    if (i >= total8) return;
    int k0 = (i * 8) & (HC - 1);
    u16x8 v = ((const u16x8*)t)[i];
    u16x8 o;
    #pragma unroll
    for (int j = 0; j < 8; ++j) {
        int k = k0 + j;
        float m = stat[k] * invN;
        float var = stat[HC + k] * invN - m * m;
        float istd = rsqrtf(var + 1e-5f);
        float sc = gam[k] * istd;
        float sh = bet[k] - m * sc;
        o[j] = rne_bf16(fmaxf(bf16_to_f(v[j]) * sc + sh, 0.f));
    }
    ((u16x8*)t)[i] = o;
}

// ---------------------------------------------------------------- pooling (BN3 inline, bf16 input)
__global__ void k_pool(const unsigned short* __restrict__ h, const int* __restrict__ batch,
                       const float* __restrict__ stat, const float* __restrict__ gam,
                       const float* __restrict__ bet, float invN,
                       float* __restrict__ pooled, float* __restrict__ cnt, int N) {
    int t = threadIdx.x;  // 0..127
    float m = stat[t] * invN;
    float var = stat[HC + t] * invN - m * m;
    float istd = rsqrtf(var + 1e-5f);
    float scv = gam[t] * istd;
    float shv = bet[t] - m * scv;
    int rpb = (N + gridDim.x - 1) / gridDim.x;
    int r0 = blockIdx.x * rpb;
    int r1 = min(N, r0 + rpb);
    if (r0 >= r1) return;
    int curb = batch[r0];
    float acc = 0.f; float c = 0.f;
    for (int r = r0; r < r1; ++r) {
        int b = batch[r];
        if (b != curb) {
            atomicAdd(&pooled[curb * HC + t], acc);
            if (t == 0) atomicAdd(&cnt[curb], c);
            curb = b; acc = 0.f; c = 0.f;
        }
        acc += bf16_to_f(h[(size_t)r * HC + t]) * scv + shv;
        c += 1.f;
    }
    atomicAdd(&pooled[curb * HC + t], acc);
    if (t == 0) atomicAdd(&cnt[curb], c);
}

// build z padded to ZKP cols (pad = 0)
__global__ void k_build_z(const float* __restrict__ pooled, const float* __restrict__ cnt,
                          const float* __restrict__ origin, const float* __restrict__ dir,
                          float* __restrict__ z, int G) {
    int g = blockIdx.x;
    int t = threadIdx.x;
    if (t >= ZKP) return;
    float v = 0.f;
    if (t < HC) {
        float c = fmaxf(cnt[g], 1.0f);
        v = pooled[g * HC + t] / c;
    } else if (t < HC + 3) {
        v = origin[g * 3 + (t - HC)];
    } else if (t < HC + 6) {
        v = dir[g * 3 + (t - HC - 3)];
    }
    z[g * ZKP + t] = v;
}

// ---------------------------------------------------------------- W prep (all 3 GCN weights)
__global__ void k_wprep_all(const float* __restrict__ W1, const float* __restrict__ W2,
                            const float* __restrict__ W3,
                            unsigned short* __restrict__ w1h, unsigned short* __restrict__ w1l,
                            unsigned short* __restrict__ w2h, unsigned short* __restrict__ w2l,
                            unsigned short* __restrict__ w3h, unsigned short* __restrict__ w3l) {
    int i = blockIdx.x * blockDim.x + threadIdx.x;
    const float* W; unsigned short *th, *tl; int K, idx;
    if (i < FIN * HC)           { W = W1; th = w1h; tl = w1l; K = FIN; idx = i; }
    else if (i < FIN*HC + HC*HC){ W = W2; th = w2h; tl = w2l; K = HC;  idx = i - FIN*HC; }
    else if (i < FIN*HC + 2*HC*HC){ W = W3; th = w3h; tl = w3l; K = HC; idx = i - FIN*HC - HC*HC; }
    else return;
    int k = idx >> 7, n = idx & (HC - 1);
    float w = W[idx];
    unsigned short h = rne_bf16(w);
    th[n * K + k] = h;
    tl[n * K + k] = rne_bf16(w - bf16_to_f(h));
}

// ---------------------------------------------------------------- W prep (head, all 3 via grid.z)
__global__ __launch_bounds__(256) void k_wprep2_all(const float* __restrict__ Wd0,
                                                    const float* __restrict__ Wd1,
                                                    const float* __restrict__ Wd2,
                                                    unsigned short* __restrict__ d0h,
                                                    unsigned short* __restrict__ d0l,
                                                    unsigned short* __restrict__ d1h,
                                                    unsigned short* __restrict__ d1l,
                                                    unsigned short* __restrict__ d2h,
                                                    unsigned short* __restrict__ d2l) {
    int z = blockIdx.z;
    const float* W; unsigned short *th, *tl; int K, KP;
    if (z == 0) {
        if (blockIdx.x >= ZKP / 32) return;
        W = Wd0; th = d0h; tl = d0l; K = ZK; KP = ZKP;
    } else if (z == 1) {
        W = Wd1; th = d1h; tl = d1l; K = DHID; KP = DHID;
    } else {
        W = Wd2; th = d2h; tl = d2l; K = DHID; KP = DHID;
    }
    __shared__ float tile[32][33];
    int kt = blockIdx.x * 32, nt = blockIdx.y * 32;
    int tx = threadIdx.x & 31, ty0 = threadIdx.x >> 5;
    #pragma unroll
    for (int i = 0; i < 4; ++i) {
        int ty = ty0 + i * 8;
        int k = kt + ty;
        float v = (k < K) ? W[(size_t)k * DHID + nt + tx] : 0.f;
        tile[ty][tx] = v;
    }
    __syncthreads();
    #pragma unroll
    for (int i = 0; i < 4; ++i) {
        int ty = ty0 + i * 8;
        int n = nt + ty;
        int k = kt + tx;
        float w = tile[tx][ty];
        unsigned short h = rne_bf16(w);
        th[(size_t)n * KP + k] = h;
        tl[(size_t)n * KP + k] = rne_bf16(w - bf16_to_f(h));
    }
}

// ---------------------------------------------------------------- MFMA node GEMM (pure bf16 A)
template <int KK, bool SCALE>
__global__ __launch_bounds__(512) void gemm_node2(const unsigned short* __restrict__ A,
                                                  const unsigned short* __restrict__ wth,
                                                  const unsigned short* __restrict__ wtl,
                                                  const float* __restrict__ dinv,
                                                  unsigned short* __restrict__ C, int M) {
    constexpr int KS = KK / 32;
    int tid = threadIdx.x;
    int lane = tid & 63, wid = tid >> 6;
    int rw = wid & 1, cg = wid >> 1;
    int l15 = lane & 15, l4 = lane >> 4;
    int cbase = cg * 32;

    FragU bh[2][KS], bl[2][KS];
    #pragma unroll
    for (int ct = 0; ct < 2; ++ct) {
        int n = cbase + ct * 16 + l15;
        #pragma unroll
        for (int ks = 0; ks < KS; ++ks) {
            int k = ks * 32 + l4 * 8;
            bh[ct][ks].s = *(const short8*)(wth + (size_t)n * KK + k);
            bl[ct][ks].s = *(const short8*)(wtl + (size_t)n * KK + k);
        }
    }

    #pragma unroll
    for (int rt = 0; rt < 2; ++rt) {
        int m0 = blockIdx.x * 64 + rt * 32 + rw * 16;
        if (m0 < M) {
            int arow = min(m0 + l15, M - 1);
            f32x4 zero = {0.f, 0.f, 0.f, 0.f};
            f32x4 acc[2] = {zero, zero};
            #pragma unroll
            for (int ks = 0; ks < KS; ++ks) {
                int k0 = ks * 32 + l4 * 8;
                FragU a;
                a.u = *(const u16x8*)(A + (size_t)arow * KK + k0);
                #pragma unroll
                for (int ct = 0; ct < 2; ++ct) {
                    acc[ct] = __builtin_amdgcn_mfma_f32_16x16x32_bf16(a.b, bh[ct][ks].b, acc[ct], 0, 0, 0);
                    acc[ct] = __builtin_amdgcn_mfma_f32_16x16x32_bf16(a.b, bl[ct][ks].b, acc[ct], 0, 0, 0);
                }
            }
            float dv0 = 1.f, dv1 = 1.f, dv2 = 1.f, dv3 = 1.f;
            if (SCALE) {
                int rbase = m0 + l4 * 4;
                dv0 = dinv[min(rbase + 0, M - 1)];
                dv1 = dinv[min(rbase + 1, M - 1)];
                dv2 = dinv[min(rbase + 2, M - 1)];
                dv3 = dinv[min(rbase + 3, M - 1)];
            }
            #pragma unroll
            for (int ct = 0; ct < 2; ++ct) {
                int col = cbase + ct * 16 + l15;
                #pragma unroll
                for (int r = 0; r < 4; ++r) {
                    int row = m0 + l4 * 4 + r;
                    if (row < M) {
                        float v = acc[ct][r];
                        if (SCALE) v *= (r == 0 ? dv0 : r == 1 ? dv1 : r == 2 ? dv2 : dv3);
                        C[(size_t)row * HC + col] = rne_bf16(v);
                    }
                }
            }
        }
    }
}

// ---------------------------------------------------------------- MFMA head GEMM, split-K
__global__ __launch_bounds__(256) void gemm_head_sk(const float* __restrict__ A,
                                                    const unsigned short* __restrict__ wth,
                                                    const unsigned short* __restrict__ wtl,
                                                    float* __restrict__ Cpart,
                                                    int M, int N, int K, int slice) {
    int tid = threadIdx.x;
    int lane = tid & 63, wid = tid >> 6;
    int rw = wid & 1, cw = wid >> 1;
    int l15 = lane & 15, l4 = lane >> 4;
    int m0 = blockIdx.y * 32 + rw * 16;
    int cb = blockIdx.x * 64 + cw * 32;
    int z = blockIdx.z;
    int kbeg = z * slice;
    int kend = min(K, kbeg + slice);
    if (m0 >= M) return;

    int arow = m0 + l15;
    f32x4 zero = {0.f, 0.f, 0.f, 0.f};
    f32x4 acc[2] = {zero, zero};

    for (int k0 = kbeg; k0 < kend; k0 += 32) {
        int ka = k0 + l4 * 8;
        const float4 p0 = *(const float4*)(A + (size_t)arow * K + ka);
        const float4 p1 = *(const float4*)(A + (size_t)arow * K + ka + 4);
        float av[8] = {p0.x, p0.y, p0.z, p0.w, p1.x, p1.y, p1.z, p1.w};
        FragU ah, al;
        #pragma unroll
        for (int i = 0; i < 8; ++i) {
            unsigned short h = rne_bf16(av[i]);
            ah.s[i] = (short)h;
            al.s[i] = (short)rne_bf16(av[i] - bf16_to_f(h));
        }
        #pragma unroll
        for (int ct = 0; ct < 2; ++ct) {
            int n = cb + ct * 16 + l15;
            FragU bh, bl;
            bh.s = *(const short8*)(wth + (size_t)n * K + ka);
            bl.s = *(const short8*)(wtl + (size_t)n * K + ka);
            acc[ct] = __builtin_amdgcn_mfma_f32_16x16x32_bf16(ah.b, bh.b, acc[ct], 0, 0, 0);
            acc[ct] = __builtin_amdgcn_mfma_f32_16x16x32_bf16(ah.b, bl.b, acc[ct], 0, 0, 0);
            acc[ct] = __builtin_amdgcn_mfma_f32_16x16x32_bf16(al.b, bh.b, acc[ct], 0, 0, 0);
        }
    }

    float* Cz = Cpart + (size_t)z * M * N;
    #pragma unroll
    for (int ct = 0; ct < 2; ++ct) {
        int col = cb + ct * 16 + l15;
        #pragma unroll
        for (int r = 0; r < 4; ++r) {
            int row = m0 + l4 * 4 + r;
            Cz[(size_t)row * N + col] = acc[ct][r];
        }
    }
}

// sum NZ partials + bias + relu; N power of two (DHID)
__global__ void k_reduce_br(const float* __restrict__ part, const float* __restrict__ bias,
                            float* __restrict__ C, int MN, int Nmask, int NZ) {
    int i = (blockIdx.x * blockDim.x + threadIdx.x) * 4;
    if (i >= MN) return;
    float4 acc = *(const float4*)(part + i);
    for (int zz = 1; zz < NZ; ++zz) {
        float4 p = *(const float4*)(part + (size_t)zz * MN + i);
        acc.x += p.x; acc.y += p.y; acc.z += p.z; acc.w += p.w;
    }
    int n = i & Nmask;
    acc.x += bias[n]; acc.y += bias[n + 1]; acc.z += bias[n + 2]; acc.w += bias[n + 3];
    acc.x = fmaxf(acc.x, 0.f); acc.y = fmaxf(acc.y, 0.f);
    acc.z = fmaxf(acc.z, 0.f); acc.w = fmaxf(acc.w, 0.f);
    *(float4*)(C + i) = acc;
}

// final [G,DH] @ [DH,3] + bout
__global__ void k_dense_out(const float* __restrict__ z, const float* __restrict__ W,
                            const float* __restrict__ b, float* __restrict__ out, int K) {
    int g = blockIdx.x;
    const float* zr = z + (size_t)g * K;
    float a0 = 0.f, a1 = 0.f, a2 = 0.f;
    for (int k = threadIdx.x; k < K; k += blockDim.x) {
        float zv = zr[k];
        a0 += zv * W[k * 3 + 0];
        a1 += zv * W[k * 3 + 1];
        a2 += zv * W[k * 3 + 2];
    }
    __shared__ float s[768];
    s[threadIdx.x] = a0; s[256 + threadIdx.x] = a1; s[512 + threadIdx.x] = a2;
    __syncthreads();
    for (int off = 128; off > 0; off >>= 1) {
        if ((int)threadIdx.x < off) {
            s[threadIdx.x]       += s[threadIdx.x + off];
            s[256 + threadIdx.x] += s[256 + threadIdx.x + off];
            s[512 + threadIdx.x] += s[512 + threadIdx.x + off];
        }
        __syncthreads();
    }
    if (threadIdx.x == 0) {
        out[g * 3 + 0] = s[0]   + b[0];
        out[g * 3 + 1] = s[256] + b[1];
        out[g * 3 + 2] = s[512] + b[2];
    }
}

// ---------------------------------------------------------------- launch
extern "C" void kernel_launch(void* const* d_in, const int* in_sizes, int n_in,
                              void* d_out, int out_size, void* d_ws, size_t ws_size,
                              hipStream_t stream) {
    const float* x         = (const float*)d_in[0];
    const float* origin    = (const float*)d_in[1];
    const float* direction = (const float*)d_in[2];
    const int*   eidx      = (const int*)d_in[3];
    const int*   batch     = (const int*)d_in[4];
    const float* W1 = (const float*)d_in[5];
    const float* W2 = (const float*)d_in[7];
    const float* W3 = (const float*)d_in[9];
    const float* g1 = (const float*)d_in[11]; const float* be1 = (const float*)d_in[12];
    const float* g2 = (const float*)d_in[13]; const float* be2 = (const float*)d_in[14];
    const float* g3 = (const float*)d_in[15]; const float* be3 = (const float*)d_in[16];
    const float* Wd0 = (const float*)d_in[17]; const float* bd0 = (const float*)d_in[18];
    const float* Wd1 = (const float*)d_in[19]; const float* bd1 = (const float*)d_in[20];
    const float* Wd2 = (const float*)d_in[21]; const float* bd2 = (const float*)d_in[22];
    const float* Wout = (const float*)d_in[23]; const float* bout = (const float*)d_in[24];
    float* out = (float*)d_out;

    const int N = in_sizes[4];
    const int E = in_sizes[3] / 2;
    const int G = in_sizes[1] / 3;
    const int* src = eidx;
    const int* dst = eidx + E;

    char* ws = (char*)d_ws;
    size_t off = 0;
    auto alloc = [&](size_t nbytes) -> void* {
        void* p = (void*)(ws + off);
        off += (nbytes + 255) & ~(size_t)255;
        return p;
    };
    // zero-init region (one memset): colstats | pooled | cntf | degcnt
    float* colstats = (float*)alloc(3 * 2 * HC * 4);
    float* pooled   = (float*)alloc((size_t)G * HC * 4);
    float* cntf     = (float*)alloc((size_t)G * 4);
    int*   degcnt   = (int*)alloc((size_t)N * 4);
    const size_t zeroBytes = 3 * 2 * HC * 4 + (size_t)G * HC * 4 + 1024 /*cntf pad*/ + (size_t)N * 4;

    float* dinv     = (float*)alloc((size_t)N * 4);
    int*   part     = (int*)alloc((size_t)N * 4);
    int*   bsum     = (int*)alloc(256 * 4);
    int*   row_start= (int*)alloc((size_t)N * 4);
    int*   rank     = (int*)alloc((size_t)E * 4);
    int*   csr      = (int*)alloc((size_t)E * 4);
    unsigned short* xb   = (unsigned short*)alloc((size_t)N * FIN * 2);
    unsigned short* aggx = (unsigned short*)alloc((size_t)N * FIN * 2);
    unsigned short* tabA = (unsigned short*)alloc((size_t)N * HC * 2);
    unsigned short* tabB = (unsigned short*)alloc((size_t)N * HC * 2);
    unsigned short* wt1h = (unsigned short*)alloc((size_t)FIN * HC * 2);
    unsigned short* wt1l = (unsigned short*)alloc((size_t)FIN * HC * 2);
    unsigned short* wt2h = (unsigned short*)alloc((size_t)HC * HC * 2);
    unsigned short* wt2l = (unsigned short*)alloc((size_t)HC * HC * 2);
    unsigned short* wt3h = (unsigned short*)alloc((size_t)HC * HC * 2);
    unsigned short* wt3l = (unsigned short*)alloc((size_t)HC * HC * 2);
    unsigned short* wd0h = (unsigned short*)alloc((size_t)DHID * ZKP * 2);
    unsigned short* wd0l = (unsigned short*)alloc((size_t)DHID * ZKP * 2);
    unsigned short* wd1h = (unsigned short*)alloc((size_t)DHID * DHID * 2);
    unsigned short* wd1l = (unsigned short*)alloc((size_t)DHID * DHID * 2);
    unsigned short* wd2h = (unsigned short*)alloc((size_t)DHID * DHID * 2);
    unsigned short* wd2l = (unsigned short*)alloc((size_t)DHID * DHID * 2);
    float* zbuf     = (float*)alloc((size_t)G * ZKP * 4);
    float* t0       = (float*)alloc((size_t)G * DHID * 4);
    float* t1       = (float*)alloc((size_t)G * DHID * 4);
    float* kpart    = (float*)alloc((size_t)8 * G * DHID * 4);   // 8 MB split-K partials
    (void)ws_size;

    const int nScanBlk = (N + 255) / 256;
    const int gemmBlk = (N + 63) / 64;
    const int gatherBlk1 = (N + 31) / 32;    // layer 1: 32 nodes/block (8 lanes/node)
    const int statsGatherBlk = 1024;         // occupancy cap 50%; atomics ~1024/addr (ok)
    const int total8 = N * HC / 8;
    const float invN = 1.0f / (float)N;

    hipMemsetAsync(colstats, 0, zeroBytes, stream);

    // ---- weight prep ----
    k_wprep_all<<<(FIN * HC + 2 * HC * HC + 255) / 256, 256, 0, stream>>>(
        W1, W2, W3, wt1h, wt1l, wt2h, wt2l, wt3h, wt3l);
    k_wprep2_all<<<dim3(DHID / 32, DHID / 32, 3), 256, 0, stream>>>(
        Wd0, Wd1, Wd2, wd0h, wd0l, wd1h, wd1l, wd2h, wd2l);

    // ---- CSR build (atomic-free scatter via rank) ----
    k_deg_rank<<<(E + 255) / 256, 256, 0, stream>>>(dst, degcnt, rank, E);
    k_scan1<<<nScanBlk, 256, 0, stream>>>(degcnt, part, bsum, dinv, N);
    k_scan23<<<nScanBlk, 256, 0, stream>>>(part, bsum, row_start, nScanBlk, N);
    k_scatter3<<<(E + 255) / 256, 256, 0, stream>>>(src, dst, rank, row_start, csr, E);

    // x -> bf16, pre-scaled by dinv
    k_xtobf<<<(N * FIN / 4 + 255) / 256, 256, 0, stream>>>(x, dinv, xb, N * FIN / 4);

    // ---- layer 1: gather(x') -> gemm -> stats0 (separate pass, 256-block) ----
    k_gather4<FIN, false><<<gatherBlk1, 256, 0, stream>>>(xb, csr, row_start, degcnt, dinv,
                                                          aggx, nullptr, N);
    gemm_node2<FIN, false><<<gemmBlk, 512, 0, stream>>>(aggx, wt1h, wt1l, nullptr, tabA, N);
    k_bn_reduce3<<<256, 256, 0, stream>>>(tabA, colstats + 0 * 2 * HC, N);

    // ---- layer 2: BN1 apply -> gemm(scale dinv) -> gather (stats fused, grid-strided) ----
    k_bn_apply3<<<(total8 + 255) / 256, 256, 0, stream>>>(tabA, colstats + 0 * 2 * HC,
                                                          g1, be1, invN, total8);
    gemm_node2<HC, true><<<gemmBlk, 512, 0, stream>>>(tabA, wt2h, wt2l, dinv, tabB, N);
    k_gather4<HC, true><<<statsGatherBlk, 256, 0, stream>>>(tabB, csr, row_start, degcnt,
                                                            dinv, tabA, colstats + 1 * 2 * HC, N);

    // ---- layer 3 ----
    k_bn_apply3<<<(total8 + 255) / 256, 256, 0, stream>>>(tabA, colstats + 1 * 2 * HC,
                                                          g2, be2, invN, total8);
    gemm_node2<HC, true><<<gemmBlk, 512, 0, stream>>>(tabA, wt3h, wt3l, dinv, tabB, N);
    k_gather4<HC, true><<<statsGatherBlk, 256, 0, stream>>>(tabB, csr, row_start, degcnt,
                                                            dinv, tabA, colstats + 2 * 2 * HC, N);

    // ---- pool (BN3 inline) + z ----
    k_pool<<<512, HC, 0, stream>>>(tabA, batch, colstats + 2 * 2 * HC, g3, be3, invN,
                                   pooled, cntf, N);
    k_build_z<<<G, 192, 0, stream>>>(pooled, cntf, origin, direction, zbuf, G);

    // ---- dense head: split-K MFMA + reduce ----
    const int MN = G * DHID;
    const int rblk = (MN / 4 + 255) / 256;

    gemm_head_sk<<<dim3(DHID / 64, (G + 31) / 32, 5), 256, 0, stream>>>(
        zbuf, wd0h, wd0l, kpart, G, DHID, ZKP, 32);
    k_reduce_br<<<rblk, 256, 0, stream>>>(kpart, bd0, t0, MN, DHID - 1, 5);

    gemm_head_sk<<<dim3(DHID / 64, (G + 31) / 32, 8), 256, 0, stream>>>(
        t0, wd1h, wd1l, kpart, G, DHID, DHID, 128);
    k_reduce_br<<<rblk, 256, 0, stream>>>(kpart, bd1, t1, MN, DHID - 1, 8);

    gemm_head_sk<<<dim3(DHID / 64, (G + 31) / 32, 8), 256, 0, stream>>>(
        t1, wd2h, wd2l, kpart, G, DHID, DHID, 128);
    k_reduce_br<<<rblk, 256, 0, stream>>>(kpart, bd2, t0, MN, DHID - 1, 8);

    k_dense_out<<<G, 256, 0, stream>>>(t0, Wout, bout, out, DHID);
}

// Round 15
// 367.672 us; speedup vs baseline: 1.0270x; 1.0270x over previous
//
#include <hip/hip_runtime.h>

#define HC 128      // hidden / latent channels
#define FIN 64
#define DHID 1024
#define ZK 134      // LAT + 6
#define ZKP 160     // ZK padded to multiple of 32 for MFMA head

typedef __attribute__((ext_vector_type(8))) short short8;
typedef __attribute__((ext_vector_type(8))) __bf16 bf16x8;
typedef __attribute__((ext_vector_type(4))) float f32x4;
typedef __attribute__((ext_vector_type(8))) unsigned short u16x8;
typedef __attribute__((ext_vector_type(4))) unsigned short u16x4;

union FragU { short8 s; bf16x8 b; u16x8 u; };

__device__ inline unsigned short rne_bf16(float x) {
    union { float f; unsigned u; } v; v.f = x;
    unsigned u = v.u;
    unsigned r = (u + 0x7fffu + ((u >> 16) & 1u)) >> 16;
    return (unsigned short)r;
}
__device__ inline float bf16_to_f(unsigned short h) {
    union { unsigned u; float f; } v; v.u = ((unsigned)h) << 16;
    return v.f;
}

// ---------------------------------------------------------------- degree + per-edge rank
__global__ void k_deg_rank(const int* __restrict__ dst, int* __restrict__ cnt,
                           int* __restrict__ rank, int E) {
    int i = blockIdx.x * blockDim.x + threadIdx.x;
    if (i < E) rank[i] = atomicAdd(&cnt[dst[i]], 1);
}

// x fp32 -> bf16 table, pre-scaled by dinv[row]
__global__ void k_xtobf(const float* __restrict__ x, const float* __restrict__ dinv,
                        unsigned short* __restrict__ xb, int n4) {
    int i = blockIdx.x * blockDim.x + threadIdx.x;
    if (i >= n4) return;
    float d = dinv[i / (FIN / 4)];
    float4 v = ((const float4*)x)[i];
    u16x4 o;
    o[0] = rne_bf16(v.x * d); o[1] = rne_bf16(v.y * d);
    o[2] = rne_bf16(v.z * d); o[3] = rne_bf16(v.w * d);
    ((u16x4*)xb)[i] = o;
}

// ---------------------------------------------------------------- scan (CSR row offsets) + dinv
__global__ void k_scan1(const int* __restrict__ cnt, int* __restrict__ part,
                        int* __restrict__ bsum, float* __restrict__ dinv, int N) {
    __shared__ int sh[256];
    int t = threadIdx.x, i = blockIdx.x * 256 + t;
    int v = (i < N) ? cnt[i] : 0;
    if (i < N) dinv[i] = rsqrtf((float)v + 1.0f);
    sh[t] = v; __syncthreads();
    #pragma unroll
    for (int off = 1; off < 256; off <<= 1) {
        int tv = (t >= off) ? sh[t - off] : 0;
        __syncthreads();
        sh[t] += tv;
        __syncthreads();
    }
    if (i < N) part[i] = sh[t] - v;
    if (t == 255) bsum[blockIdx.x] = sh[255];
}

// merged scan2+scan3: each block computes its bsum prefix itself (nb <= 256)
__global__ void k_scan23(const int* __restrict__ part, const int* __restrict__ bsum,
                         int* __restrict__ row_start, int nb, int N) {
    __shared__ int sh[256];
    int t = threadIdx.x, b = blockIdx.x;
    sh[t] = (t < b && t < nb) ? bsum[t] : 0;
    __syncthreads();
    #pragma unroll
    for (int off = 128; off > 0; off >>= 1) {
        if (t < off) sh[t] += sh[t + off];
        __syncthreads();
    }
    int prefix = sh[0];
    int i = b * 256 + t;
    if (i < N) row_start[i] = part[i] + prefix;
}

// atomic-free scatter: pos = row_start[d] + rank[e]
__global__ void k_scatter3(const int* __restrict__ src, const int* __restrict__ dst,
                           const int* __restrict__ rank, const int* __restrict__ row_start,
                           int* __restrict__ csr, int E) {
    int e = blockIdx.x * blockDim.x + threadIdx.x;
    if (e >= E) return;
    int d = dst[e];
    csr[row_start[d] + rank[e]] = src[e];
}

// ---------------------------------------------------------------- gather (pre-scaled bf16 table)
// agg[d] = dinv[d] * (T'[d] + sum T'[src]).  STATS: grid-strided 512 blocks (proven
// config — round 13: 1024 blocks regressed via atomic-tail; 3125 via 800k atomics).
template <int RF> struct BVec;
template <> struct BVec<64>  { using T = u16x4; static const int VPL = 4; };
template <> struct BVec<128> { using T = u16x8; static const int VPL = 8; };

template <int RF, bool STATS>
__global__ __launch_bounds__(256) void k_gather4(const unsigned short* __restrict__ T,
                                                 const int* __restrict__ csr,
                                                 const int* __restrict__ row_start,
                                                 const int* __restrict__ cnt,
                                                 const float* __restrict__ dinv,
                                                 unsigned short* __restrict__ agg,
                                                 float* __restrict__ stat, int N) {
    using vec = typename BVec<RF>::T;
    constexpr int VPL = BVec<RF>::VPL;
    int tid = threadIdx.x;
    int slot = tid >> 4, q = tid & 15;
    int numGrp = (N + 15) >> 4;
    float s0=0.f,s1=0.f,s2=0.f,s3=0.f,s4=0.f,s5=0.f,s6=0.f,s7=0.f;
    float p0=0.f,p1=0.f,p2=0.f,p3=0.f,p4=0.f,p5=0.f,p6=0.f,p7=0.f;

    for (int grp = blockIdx.x; grp < numGrp; grp += gridDim.x) {
        int node = grp * 16 + slot;
        if (node >= N) continue;
        int beg = row_start[node];
        int end = beg + cnt[node];
        float d = dinv[node];
        vec sv = ((const vec*)(T + (size_t)node * RF))[q];
        float acc[VPL];
        #pragma unroll
        for (int i = 0; i < VPL; ++i) acc[i] = bf16_to_f(sv[i]);
        int j = beg;
        for (; j + 8 <= end; j += 8) {
            int e0 = csr[j], e1 = csr[j+1], e2 = csr[j+2], e3 = csr[j+3];
            int e4 = csr[j+4], e5 = csr[j+5], e6 = csr[j+6], e7 = csr[j+7];
            vec v0 = ((const vec*)(T + (size_t)e0 * RF))[q];
            vec v1 = ((const vec*)(T + (size_t)e1 * RF))[q];
            vec v2 = ((const vec*)(T + (size_t)e2 * RF))[q];
            vec v3 = ((const vec*)(T + (size_t)e3 * RF))[q];
            vec v4 = ((const vec*)(T + (size_t)e4 * RF))[q];
            vec v5 = ((const vec*)(T + (size_t)e5 * RF))[q];
            vec v6 = ((const vec*)(T + (size_t)e6 * RF))[q];
            vec v7 = ((const vec*)(T + (size_t)e7 * RF))[q];
            #pragma unroll
            for (int i = 0; i < VPL; ++i) {
                acc[i] += (bf16_to_f(v0[i]) + bf16_to_f(v1[i]))
                        + (bf16_to_f(v2[i]) + bf16_to_f(v3[i]))
                        + (bf16_to_f(v4[i]) + bf16_to_f(v5[i]))
                        + (bf16_to_f(v6[i]) + bf16_to_f(v7[i]));
            }
        }
        for (; j + 2 <= end; j += 2) {
            int e0 = csr[j], e1 = csr[j + 1];
            vec v0 = ((const vec*)(T + (size_t)e0 * RF))[q];
            vec v1 = ((const vec*)(T + (size_t)e1 * RF))[q];
            #pragma unroll
            for (int i = 0; i < VPL; ++i)
                acc[i] += bf16_to_f(v0[i]) + bf16_to_f(v1[i]);
        }
        if (j < end) {
            int e0 = csr[j];
            vec v0 = ((const vec*)(T + (size_t)e0 * RF))[q];
            #pragma unroll
            for (int i = 0; i < VPL; ++i) acc[i] += bf16_to_f(v0[i]);
        }
        vec o;
        #pragma unroll
        for (int i = 0; i < VPL; ++i) o[i] = rne_bf16(acc[i] * d);
        ((vec*)(agg + (size_t)node * RF))[q] = o;
        if (STATS) {
            float f;
            f = bf16_to_f(o[0]); s0 += f; p0 += f * f;
            f = bf16_to_f(o[1]); s1 += f; p1 += f * f;
            f = bf16_to_f(o[2]); s2 += f; p2 += f * f;
            f = bf16_to_f(o[3]); s3 += f; p3 += f * f;
            if (VPL == 8) {
                f = bf16_to_f(o[4]); s4 += f; p4 += f * f;
                f = bf16_to_f(o[5]); s5 += f; p5 += f * f;
                f = bf16_to_f(o[6]); s6 += f; p6 += f * f;
                f = bf16_to_f(o[7]); s7 += f; p7 += f * f;
            }
        }
    }

    if (STATS) {
        __shared__ float sh[16][136];
        int c0 = q * 8;
        sh[slot][c0+0]=s0; sh[slot][c0+1]=s1; sh[slot][c0+2]=s2; sh[slot][c0+3]=s3;
        sh[slot][c0+4]=s4; sh[slot][c0+5]=s5; sh[slot][c0+6]=s6; sh[slot][c0+7]=s7;
        __syncthreads();
        if (tid < HC) {
            float tot = 0.f;
            #pragma unroll
            for (int r = 0; r < 16; ++r) tot += sh[r][tid];
            atomicAdd(&stat[tid], tot);
        }
        __syncthreads();
        sh[slot][c0+0]=p0; sh[slot][c0+1]=p1; sh[slot][c0+2]=p2; sh[slot][c0+3]=p3;
        sh[slot][c0+4]=p4; sh[slot][c0+5]=p5; sh[slot][c0+6]=p6; sh[slot][c0+7]=p7;
        __syncthreads();
        if (tid < HC) {
            float tot = 0.f;
            #pragma unroll
            for (int r = 0; r < 16; ++r) tot += sh[r][tid];
            atomicAdd(&stat[HC + tid], tot);
        }
    }
}

// ---------------------------------------------------------------- batchnorm stats (layer 1: on gemm output)
__global__ __launch_bounds__(256) void k_bn_reduce3(const unsigned short* __restrict__ x,
                                                    float* __restrict__ stat, int N) {
    int cg = threadIdx.x & 15;
    int rr = threadIdx.x >> 4;
    int rpb = (N + gridDim.x - 1) / gridDim.x;
    int r0 = blockIdx.x * rpb;
    int r1 = min(N, r0 + rpb);
    float s0=0.f,s1=0.f,s2=0.f,s3=0.f,s4=0.f,s5=0.f,s6=0.f,s7=0.f;
    float q0=0.f,q1=0.f,q2=0.f,q3=0.f,q4=0.f,q5=0.f,q6=0.f,q7=0.f;
    for (int r = r0 + rr; r < r1; r += 16) {
        u16x8 v = *(const u16x8*)(x + (size_t)r * HC + cg * 8);
        float f;
        f = bf16_to_f(v[0]); s0 += f; q0 += f * f;
        f = bf16_to_f(v[1]); s1 += f; q1 += f * f;
        f = bf16_to_f(v[2]); s2 += f; q2 += f * f;
        f = bf16_to_f(v[3]); s3 += f; q3 += f * f;
        f = bf16_to_f(v[4]); s4 += f; q4 += f * f;
        f = bf16_to_f(v[5]); s5 += f; q5 += f * f;
        f = bf16_to_f(v[6]); s6 += f; q6 += f * f;
        f = bf16_to_f(v[7]); s7 += f; q7 += f * f;
    }
    __shared__ float sh[16][136];
    int c0 = cg * 8;
    int tid = threadIdx.x;
    sh[rr][c0+0]=s0; sh[rr][c0+1]=s1; sh[rr][c0+2]=s2; sh[rr][c0+3]=s3;
    sh[rr][c0+4]=s4; sh[rr][c0+5]=s5; sh[rr][c0+6]=s6; sh[rr][c0+7]=s7;
    __syncthreads();
    if (tid < HC) {
        float tot = 0.f;
        #pragma unroll
        for (int r2 = 0; r2 < 16; ++r2) tot += sh[r2][tid];
        atomicAdd(&stat[tid], tot);
    }
    __syncthreads();
    sh[rr][c0+0]=q0; sh[rr][c0+1]=q1; sh[rr][c0+2]=q2; sh[rr][c0+3]=q3;
    sh[rr][c0+4]=q4; sh[rr][c0+5]=q5; sh[rr][c0+6]=q6; sh[rr][c0+7]=q7;
    __syncthreads();
    if (tid < HC) {
        float tot = 0.f;
        #pragma unroll
        for (int r2 = 0; r2 < 16; ++r2) tot += sh[r2][tid];
        atomicAdd(&stat[HC + tid], tot);
    }
}

// in-place BN+ReLU on bf16 table; scale/shift recomputed inline from stats
__global__ void k_bn_apply3(unsigned short* __restrict__ t, const float* __restrict__ stat,
                            const float* __restrict__ gam, const float* __restrict__ bet,
                            float invN, int total8) {
    int i = blockIdx.x * blockDim.x + threadIdx.x;
    if (i >= total8) return;
    int k0 = (i * 8) & (HC - 1);
    u16x8 v = ((const u16x8*)t)[i];
    u16x8 o;
    #pragma unroll
    for (int j = 0; j < 8; ++j) {
        int k = k0 + j;
        float m = stat[k] * invN;
        float var = stat[HC + k] * invN - m * m;
        float istd = rsqrtf(var + 1e-5f);
        float sc = gam[k] * istd;
        float sh = bet[k] - m * sc;
        o[j] = rne_bf16(fmaxf(bf16_to_f(v[j]) * sc + sh, 0.f));
    }
    ((u16x8*)t)[i] = o;
}

// ---------------------------------------------------------------- pooling (BN3 inline, bf16 input)
__global__ void k_pool(const unsigned short* __restrict__ h, const int* __restrict__ batch,
                       const float* __restrict__ stat, const float* __restrict__ gam,
                       const float* __restrict__ bet, float invN,
                       float* __restrict__ pooled, float* __restrict__ cnt, int N) {
    int t = threadIdx.x;  // 0..127
    float m = stat[t] * invN;
    float var = stat[HC + t] * invN - m * m;
    float istd = rsqrtf(var + 1e-5f);
    float scv = gam[t] * istd;
    float shv = bet[t] - m * scv;
    int rpb = (N + gridDim.x - 1) / gridDim.x;
    int r0 = blockIdx.x * rpb;
    int r1 = min(N, r0 + rpb);
    if (r0 >= r1) return;
    int curb = batch[r0];
    float acc = 0.f; float c = 0.f;
    for (int r = r0; r < r1; ++r) {
        int b = batch[r];
        if (b != curb) {
            atomicAdd(&pooled[curb * HC + t], acc);
            if (t == 0) atomicAdd(&cnt[curb], c);
            curb = b; acc = 0.f; c = 0.f;
        }
        acc += bf16_to_f(h[(size_t)r * HC + t]) * scv + shv;
        c += 1.f;
    }
    atomicAdd(&pooled[curb * HC + t], acc);
    if (t == 0) atomicAdd(&cnt[curb], c);
}

// build z padded to ZKP cols (pad = 0)
__global__ void k_build_z(const float* __restrict__ pooled, const float* __restrict__ cnt,
                          const float* __restrict__ origin, const float* __restrict__ dir,
                          float* __restrict__ z, int G) {
    int g = blockIdx.x;
    int t = threadIdx.x;
    if (t >= ZKP) return;
    float v = 0.f;
    if (t < HC) {
        float c = fmaxf(cnt[g], 1.0f);
        v = pooled[g * HC + t] / c;
    } else if (t < HC + 3) {
        v = origin[g * 3 + (t - HC)];
    } else if (t < HC + 6) {
        v = dir[g * 3 + (t - HC - 3)];
    }
    z[g * ZKP + t] = v;
}

// ---------------------------------------------------------------- W prep (all 3 GCN weights)
__global__ void k_wprep_all(const float* __restrict__ W1, const float* __restrict__ W2,
                            const float* __restrict__ W3,
                            unsigned short* __restrict__ w1h, unsigned short* __restrict__ w1l,
                            unsigned short* __restrict__ w2h, unsigned short* __restrict__ w2l,
                            unsigned short* __restrict__ w3h, unsigned short* __restrict__ w3l) {
    int i = blockIdx.x * blockDim.x + threadIdx.x;
    const float* W; unsigned short *th, *tl; int K, idx;
    if (i < FIN * HC)           { W = W1; th = w1h; tl = w1l; K = FIN; idx = i; }
    else if (i < FIN*HC + HC*HC){ W = W2; th = w2h; tl = w2l; K = HC;  idx = i - FIN*HC; }
    else if (i < FIN*HC + 2*HC*HC){ W = W3; th = w3h; tl = w3l; K = HC; idx = i - FIN*HC - HC*HC; }
    else return;
    int k = idx >> 7, n = idx & (HC - 1);
    float w = W[idx];
    unsigned short h = rne_bf16(w);
    th[n * K + k] = h;
    tl[n * K + k] = rne_bf16(w - bf16_to_f(h));
}

// ---------------------------------------------------------------- W prep (head, all 3 via grid.z)
__global__ __launch_bounds__(256) void k_wprep2_all(const float* __restrict__ Wd0,
                                                    const float* __restrict__ Wd1,
                                                    const float* __restrict__ Wd2,
                                                    unsigned short* __restrict__ d0h,
                                                    unsigned short* __restrict__ d0l,
                                                    unsigned short* __restrict__ d1h,
                                                    unsigned short* __restrict__ d1l,
                                                    unsigned short* __restrict__ d2h,
                                                    unsigned short* __restrict__ d2l) {
    int z = blockIdx.z;
    const float* W; unsigned short *th, *tl; int K, KP;
    if (z == 0) {
        if (blockIdx.x >= ZKP / 32) return;
        W = Wd0; th = d0h; tl = d0l; K = ZK; KP = ZKP;
    } else if (z == 1) {
        W = Wd1; th = d1h; tl = d1l; K = DHID; KP = DHID;
    } else {
        W = Wd2; th = d2h; tl = d2l; K = DHID; KP = DHID;
    }
    __shared__ float tile[32][33];
    int kt = blockIdx.x * 32, nt = blockIdx.y * 32;
    int tx = threadIdx.x & 31, ty0 = threadIdx.x >> 5;
    #pragma unroll
    for (int i = 0; i < 4; ++i) {
        int ty = ty0 + i * 8;
        int k = kt + ty;
        float v = (k < K) ? W[(size_t)k * DHID + nt + tx] : 0.f;
        tile[ty][tx] = v;
    }
    __syncthreads();
    #pragma unroll
    for (int i = 0; i < 4; ++i) {
        int ty = ty0 + i * 8;
        int n = nt + ty;
        int k = kt + tx;
        float w = tile[tx][ty];
        unsigned short h = rne_bf16(w);
        th[(size_t)n * KP + k] = h;
        tl[(size_t)n * KP + k] = rne_bf16(w - bf16_to_f(h));
    }
}

// ---------------------------------------------------------------- MFMA node GEMM (pure bf16 A)
template <int KK, bool SCALE>
__global__ __launch_bounds__(512) void gemm_node2(const unsigned short* __restrict__ A,
                                                  const unsigned short* __restrict__ wth,
                                                  const unsigned short* __restrict__ wtl,
                                                  const float* __restrict__ dinv,
                                                  unsigned short* __restrict__ C, int M) {
    constexpr int KS = KK / 32;
    int tid = threadIdx.x;
    int lane = tid & 63, wid = tid >> 6;
    int rw = wid & 1, cg = wid >> 1;
    int l15 = lane & 15, l4 = lane >> 4;
    int cbase = cg * 32;

    FragU bh[2][KS], bl[2][KS];
    #pragma unroll
    for (int ct = 0; ct < 2; ++ct) {
        int n = cbase + ct * 16 + l15;
        #pragma unroll
        for (int ks = 0; ks < KS; ++ks) {
            int k = ks * 32 + l4 * 8;
            bh[ct][ks].s = *(const short8*)(wth + (size_t)n * KK + k);
            bl[ct][ks].s = *(const short8*)(wtl + (size_t)n * KK + k);
        }
    }

    #pragma unroll
    for (int rt = 0; rt < 2; ++rt) {
        int m0 = blockIdx.x * 64 + rt * 32 + rw * 16;
        if (m0 < M) {
            int arow = min(m0 + l15, M - 1);
            f32x4 zero = {0.f, 0.f, 0.f, 0.f};
            f32x4 acc[2] = {zero, zero};
            #pragma unroll
            for (int ks = 0; ks < KS; ++ks) {
                int k0 = ks * 32 + l4 * 8;
                FragU a;
                a.u = *(const u16x8*)(A + (size_t)arow * KK + k0);
                #pragma unroll
                for (int ct = 0; ct < 2; ++ct) {
                    acc[ct] = __builtin_amdgcn_mfma_f32_16x16x32_bf16(a.b, bh[ct][ks].b, acc[ct], 0, 0, 0);
                    acc[ct] = __builtin_amdgcn_mfma_f32_16x16x32_bf16(a.b, bl[ct][ks].b, acc[ct], 0, 0, 0);
                }
            }
            float dv0 = 1.f, dv1 = 1.f, dv2 = 1.f, dv3 = 1.f;
            if (SCALE) {
                int rbase = m0 + l4 * 4;
                dv0 = dinv[min(rbase + 0, M - 1)];
                dv1 = dinv[min(rbase + 1, M - 1)];
                dv2 = dinv[min(rbase + 2, M - 1)];
                dv3 = dinv[min(rbase + 3, M - 1)];
            }
            #pragma unroll
            for (int ct = 0; ct < 2; ++ct) {
                int col = cbase + ct * 16 + l15;
                #pragma unroll
                for (int r = 0; r < 4; ++r) {
                    int row = m0 + l4 * 4 + r;
                    if (row < M) {
                        float v = acc[ct][r];
                        if (SCALE) v *= (r == 0 ? dv0 : r == 1 ? dv1 : r == 2 ? dv2 : dv3);
                        C[(size_t)row * HC + col] = rne_bf16(v);
                    }
                }
            }
        }
    }
}

// ---------------------------------------------------------------- MFMA head GEMM, split-K
__global__ __launch_bounds__(256) void gemm_head_sk(const float* __restrict__ A,
                                                    const unsigned short* __restrict__ wth,
                                                    const unsigned short* __restrict__ wtl,
                                                    float* __restrict__ Cpart,
                                                    int M, int N, int K, int slice) {
    int tid = threadIdx.x;
    int lane = tid & 63, wid = tid >> 6;
    int rw = wid & 1, cw = wid >> 1;
    int l15 = lane & 15, l4 = lane >> 4;
    int m0 = blockIdx.y * 32 + rw * 16;
    int cb = blockIdx.x * 64 + cw * 32;
    int z = blockIdx.z;
    int kbeg = z * slice;
    int kend = min(K, kbeg + slice);
    if (m0 >= M) return;

    int arow = m0 + l15;
    f32x4 zero = {0.f, 0.f, 0.f, 0.f};
    f32x4 acc[2] = {zero, zero};

    for (int k0 = kbeg; k0 < kend; k0 += 32) {
        int ka = k0 + l4 * 8;
        const float4 p0 = *(const float4*)(A + (size_t)arow * K + ka);
        const float4 p1 = *(const float4*)(A + (size_t)arow * K + ka + 4);
        float av[8] = {p0.x, p0.y, p0.z, p0.w, p1.x, p1.y, p1.z, p1.w};
        FragU ah, al;
        #pragma unroll
        for (int i = 0; i < 8; ++i) {
            unsigned short h = rne_bf16(av[i]);
            ah.s[i] = (short)h;
            al.s[i] = (short)rne_bf16(av[i] - bf16_to_f(h));
        }
        #pragma unroll
        for (int ct = 0; ct < 2; ++ct) {
            int n = cb + ct * 16 + l15;
            FragU bh, bl;
            bh.s = *(const short8*)(wth + (size_t)n * K + ka);
            bl.s = *(const short8*)(wtl + (size_t)n * K + ka);
            acc[ct] = __builtin_amdgcn_mfma_f32_16x16x32_bf16(ah.b, bh.b, acc[ct], 0, 0, 0);
            acc[ct] = __builtin_amdgcn_mfma_f32_16x16x32_bf16(ah.b, bl.b, acc[ct], 0, 0, 0);
            acc[ct] = __builtin_amdgcn_mfma_f32_16x16x32_bf16(al.b, bh.b, acc[ct], 0, 0, 0);
        }
    }

    float* Cz = Cpart + (size_t)z * M * N;
    #pragma unroll
    for (int ct = 0; ct < 2; ++ct) {
        int col = cb + ct * 16 + l15;
        #pragma unroll
        for (int r = 0; r < 4; ++r) {
            int row = m0 + l4 * 4 + r;
            Cz[(size_t)row * N + col] = acc[ct][r];
        }
    }
}

// sum NZ partials + bias + relu; N power of two (DHID)
__global__ void k_reduce_br(const float* __restrict__ part, const float* __restrict__ bias,
                            float* __restrict__ C, int MN, int Nmask, int NZ) {
    int i = (blockIdx.x * blockDim.x + threadIdx.x) * 4;
    if (i >= MN) return;
    float4 acc = *(const float4*)(part + i);
    for (int zz = 1; zz < NZ; ++zz) {
        float4 p = *(const float4*)(part + (size_t)zz * MN + i);
        acc.x += p.x; acc.y += p.y; acc.z += p.z; acc.w += p.w;
    }
    int n = i & Nmask;
    acc.x += bias[n]; acc.y += bias[n + 1]; acc.z += bias[n + 2]; acc.w += bias[n + 3];
    acc.x = fmaxf(acc.x, 0.f); acc.y = fmaxf(acc.y, 0.f);
    acc.z = fmaxf(acc.z, 0.f); acc.w = fmaxf(acc.w, 0.f);
    *(float4*)(C + i) = acc;
}

// final [G,DH] @ [DH,3] + bout
__global__ void k_dense_out(const float* __restrict__ z, const float* __restrict__ W,
                            const float* __restrict__ b, float* __restrict__ out, int K) {
    int g = blockIdx.x;
    const float* zr = z + (size_t)g * K;
    float a0 = 0.f, a1 = 0.f, a2 = 0.f;
    for (int k = threadIdx.x; k < K; k += blockDim.x) {
        float zv = zr[k];
        a0 += zv * W[k * 3 + 0];
        a1 += zv * W[k * 3 + 1];
        a2 += zv * W[k * 3 + 2];
    }
    __shared__ float s[768];
    s[threadIdx.x] = a0; s[256 + threadIdx.x] = a1; s[512 + threadIdx.x] = a2;
    __syncthreads();
    for (int off = 128; off > 0; off >>= 1) {
        if ((int)threadIdx.x < off) {
            s[threadIdx.x]       += s[threadIdx.x + off];
            s[256 + threadIdx.x] += s[256 + threadIdx.x + off];
            s[512 + threadIdx.x] += s[512 + threadIdx.x + off];
        }
        __syncthreads();
    }
    if (threadIdx.x == 0) {
        out[g * 3 + 0] = s[0]   + b[0];
        out[g * 3 + 1] = s[256] + b[1];
        out[g * 3 + 2] = s[512] + b[2];
    }
}

// ---------------------------------------------------------------- launch
extern "C" void kernel_launch(void* const* d_in, const int* in_sizes, int n_in,
                              void* d_out, int out_size, void* d_ws, size_t ws_size,
                              hipStream_t stream) {
    const float* x         = (const float*)d_in[0];
    const float* origin    = (const float*)d_in[1];
    const float* direction = (const float*)d_in[2];
    const int*   eidx      = (const int*)d_in[3];
    const int*   batch     = (const int*)d_in[4];
    const float* W1 = (const float*)d_in[5];
    const float* W2 = (const float*)d_in[7];
    const float* W3 = (const float*)d_in[9];
    const float* g1 = (const float*)d_in[11]; const float* be1 = (const float*)d_in[12];
    const float* g2 = (const float*)d_in[13]; const float* be2 = (const float*)d_in[14];
    const float* g3 = (const float*)d_in[15]; const float* be3 = (const float*)d_in[16];
    const float* Wd0 = (const float*)d_in[17]; const float* bd0 = (const float*)d_in[18];
    const float* Wd1 = (const float*)d_in[19]; const float* bd1 = (const float*)d_in[20];
    const float* Wd2 = (const float*)d_in[21]; const float* bd2 = (const float*)d_in[22];
    const float* Wout = (const float*)d_in[23]; const float* bout = (const float*)d_in[24];
    float* out = (float*)d_out;

    const int N = in_sizes[4];
    const int E = in_sizes[3] / 2;
    const int G = in_sizes[1] / 3;
    const int* src = eidx;
    const int* dst = eidx + E;

    char* ws = (char*)d_ws;
    size_t off = 0;
    auto alloc = [&](size_t nbytes) -> void* {
        void* p = (void*)(ws + off);
        off += (nbytes + 255) & ~(size_t)255;
        return p;
    };
    // zero-init region (one memset): colstats | pooled | cntf | degcnt
    float* colstats = (float*)alloc(3 * 2 * HC * 4);
    float* pooled   = (float*)alloc((size_t)G * HC * 4);
    float* cntf     = (float*)alloc((size_t)G * 4);
    int*   degcnt   = (int*)alloc((size_t)N * 4);
    const size_t zeroBytes = 3 * 2 * HC * 4 + (size_t)G * HC * 4 + 1024 /*cntf pad*/ + (size_t)N * 4;

    float* dinv     = (float*)alloc((size_t)N * 4);
    int*   part     = (int*)alloc((size_t)N * 4);
    int*   bsum     = (int*)alloc(256 * 4);
    int*   row_start= (int*)alloc((size_t)N * 4);
    int*   rank     = (int*)alloc((size_t)E * 4);
    int*   csr      = (int*)alloc((size_t)E * 4);
    unsigned short* xb   = (unsigned short*)alloc((size_t)N * FIN * 2);
    unsigned short* aggx = (unsigned short*)alloc((size_t)N * FIN * 2);
    unsigned short* tabA = (unsigned short*)alloc((size_t)N * HC * 2);
    unsigned short* tabB = (unsigned short*)alloc((size_t)N * HC * 2);
    unsigned short* wt1h = (unsigned short*)alloc((size_t)FIN * HC * 2);
    unsigned short* wt1l = (unsigned short*)alloc((size_t)FIN * HC * 2);
    unsigned short* wt2h = (unsigned short*)alloc((size_t)HC * HC * 2);
    unsigned short* wt2l = (unsigned short*)alloc((size_t)HC * HC * 2);
    unsigned short* wt3h = (unsigned short*)alloc((size_t)HC * HC * 2);
    unsigned short* wt3l = (unsigned short*)alloc((size_t)HC * HC * 2);
    unsigned short* wd0h = (unsigned short*)alloc((size_t)DHID * ZKP * 2);
    unsigned short* wd0l = (unsigned short*)alloc((size_t)DHID * ZKP * 2);
    unsigned short* wd1h = (unsigned short*)alloc((size_t)DHID * DHID * 2);
    unsigned short* wd1l = (unsigned short*)alloc((size_t)DHID * DHID * 2);
    unsigned short* wd2h = (unsigned short*)alloc((size_t)DHID * DHID * 2);
    unsigned short* wd2l = (unsigned short*)alloc((size_t)DHID * DHID * 2);
    float* zbuf     = (float*)alloc((size_t)G * ZKP * 4);
    float* t0       = (float*)alloc((size_t)G * DHID * 4);
    float* t1       = (float*)alloc((size_t)G * DHID * 4);
    float* kpart    = (float*)alloc((size_t)8 * G * DHID * 4);   // 8 MB split-K partials
    (void)ws_size;

    const int nScanBlk = (N + 255) / 256;
    const int gemmBlk = (N + 63) / 64;
    const int gatherBlk = (N + 15) / 16;
    const int statsGatherBlk = 512;          // proven best (r13); 1024 regressed (r14)
    const int total8 = N * HC / 8;
    const float invN = 1.0f / (float)N;

    hipMemsetAsync(colstats, 0, zeroBytes, stream);

    // ---- weight prep ----
    k_wprep_all<<<(FIN * HC + 2 * HC * HC + 255) / 256, 256, 0, stream>>>(
        W1, W2, W3, wt1h, wt1l, wt2h, wt2l, wt3h, wt3l);
    k_wprep2_all<<<dim3(DHID / 32, DHID / 32, 3), 256, 0, stream>>>(
        Wd0, Wd1, Wd2, wd0h, wd0l, wd1h, wd1l, wd2h, wd2l);

    // ---- CSR build (atomic-free scatter via rank) ----
    k_deg_rank<<<(E + 255) / 256, 256, 0, stream>>>(dst, degcnt, rank, E);
    k_scan1<<<nScanBlk, 256, 0, stream>>>(degcnt, part, bsum, dinv, N);
    k_scan23<<<nScanBlk, 256, 0, stream>>>(part, bsum, row_start, nScanBlk, N);
    k_scatter3<<<(E + 255) / 256, 256, 0, stream>>>(src, dst, rank, row_start, csr, E);

    // x -> bf16, pre-scaled by dinv
    k_xtobf<<<(N * FIN / 4 + 255) / 256, 256, 0, stream>>>(x, dinv, xb, N * FIN / 4);

    // ---- layer 1: gather(x') -> gemm -> stats0 (separate pass, 256-block) ----
    k_gather4<FIN, false><<<gatherBlk, 256, 0, stream>>>(xb, csr, row_start, degcnt, dinv,
                                                         aggx, nullptr, N);
    gemm_node2<FIN, false><<<gemmBlk, 512, 0, stream>>>(aggx, wt1h, wt1l, nullptr, tabA, N);
    k_bn_reduce3<<<256, 256, 0, stream>>>(tabA, colstats + 0 * 2 * HC, N);

    // ---- layer 2: BN1 apply -> gemm(scale dinv) -> gather (stats fused, grid-strided) ----
    k_bn_apply3<<<(total8 + 255) / 256, 256, 0, stream>>>(tabA, colstats + 0 * 2 * HC,
                                                          g1, be1, invN, total8);
    gemm_node2<HC, true><<<gemmBlk, 512, 0, stream>>>(tabA, wt2h, wt2l, dinv, tabB, N);
    k_gather4<HC, true><<<statsGatherBlk, 256, 0, stream>>>(tabB, csr, row_start, degcnt,
                                                            dinv, tabA, colstats + 1 * 2 * HC, N);

    // ---- layer 3 ----
    k_bn_apply3<<<(total8 + 255) / 256, 256, 0, stream>>>(tabA, colstats + 1 * 2 * HC,
                                                          g2, be2, invN, total8);
    gemm_node2<HC, true><<<gemmBlk, 512, 0, stream>>>(tabA, wt3h, wt3l, dinv, tabB, N);
    k_gather4<HC, true><<<statsGatherBlk, 256, 0, stream>>>(tabB, csr, row_start, degcnt,
                                                            dinv, tabA, colstats + 2 * 2 * HC, N);

    // ---- pool (BN3 inline) + z ----
    k_pool<<<512, HC, 0, stream>>>(tabA, batch, colstats + 2 * 2 * HC, g3, be3, invN,
                                   pooled, cntf, N);
    k_build_z<<<G, 192, 0, stream>>>(pooled, cntf, origin, direction, zbuf, G);

    // ---- dense head: split-K MFMA + reduce ----
    const int MN = G * DHID;
    const int rblk = (MN / 4 + 255) / 256;

    gemm_head_sk<<<dim3(DHID / 64, (G + 31) / 32, 5), 256, 0, stream>>>(
        zbuf, wd0h, wd0l, kpart, G, DHID, ZKP, 32);
    k_reduce_br<<<rblk, 256, 0, stream>>>(kpart, bd0, t0, MN, DHID - 1, 5);

    gemm_head_sk<<<dim3(DHID / 64, (G + 31) / 32, 8), 256, 0, stream>>>(
        t0, wd1h, wd1l, kpart, G, DHID, DHID, 128);
    k_reduce_br<<<rblk, 256, 0, stream>>>(kpart, bd1, t1, MN, DHID - 1, 8);

    gemm_head_sk<<<dim3(DHID / 64, (G + 31) / 32, 8), 256, 0, stream>>>(
        t1, wd2h, wd2l, kpart, G, DHID, DHID, 128);
    k_reduce_br<<<rblk, 256, 0, stream>>>(kpart, bd2, t0, MN, DHID - 1, 8);

    k_dense_out<<<G, 256, 0, stream>>>(t0, Wout, bout, out, DHID);
}